// Round 13
// baseline (389.167 us; speedup 1.0000x reference)
//
#include <hip/hip_runtime.h>
#include <hip/hip_bf16.h>

using u16 = unsigned short;
using u32 = unsigned int;

typedef short bf16x8 __attribute__((ext_vector_type(8)));
typedef float f32x4 __attribute__((ext_vector_type(4)));

#define AS1 __attribute__((address_space(1)))
#define AS3 __attribute__((address_space(3)))

__device__ __forceinline__ void gll16(const void* g, void* l) {
  __builtin_amdgcn_global_load_lds((const AS1 u32*)g, (AS3 u32*)l, 16, 0, 0);
}

__device__ __forceinline__ u16 f2bf(float x) {  // round-to-nearest-even bf16
  u32 u = __builtin_bit_cast(u32, x);
  u32 r = (u + 0x7fffu + ((u >> 16) & 1u)) >> 16;
  return (u16)r;
}
__device__ __forceinline__ u32 pk2(float lo, float hi) {
  return (u32)f2bf(lo) | ((u32)f2bf(hi) << 16);
}
__device__ __forceinline__ u16 f2bf_fast(float x) {  // hw cvt (validated r5/r6)
  __hip_bfloat16 h = __float2bfloat16(x);
  return __builtin_bit_cast(u16, h);
}

// ---------------- merged prep: x cast (blocks 0..4095) + 4 weight transposes ----------------
__device__ __forceinline__ void trans64(const float* __restrict__ in, u16* __restrict__ out,
                                        int R, int Cc, int bx, int by, float (*tl)[65]) {
  int c0 = bx * 64, r0 = by * 64, tid = threadIdx.x;
#pragma unroll
  for (int i = 0; i < 16; i++) {
    int idx = i * 256 + tid; int tr = idx >> 6, tc = idx & 63;
    tl[tr][tc] = in[(size_t)(r0 + tr) * Cc + c0 + tc];
  }
  __syncthreads();
#pragma unroll
  for (int i = 0; i < 16; i++) {
    int idx = i * 256 + tid; int tr = idx >> 6, tc = idx & 63;
    out[(size_t)(c0 + tr) * R + r0 + tc] = f2bf(tl[tc][tr]);
  }
}

__global__ void k_prep(const float* __restrict__ x, u16* __restrict__ xb,
                       const float* __restrict__ wq, u16* __restrict__ wqt,
                       const float* __restrict__ wk, const float* __restrict__ wv,
                       u16* __restrict__ wkvt,
                       const float* __restrict__ wo, u16* __restrict__ wot) {
  __shared__ float tl[64][65];
  int gid = blockIdx.x;
  if (gid < 4096) {
    int i = gid * 256 + threadIdx.x;
    const float4* p = (const float4*)(x + (size_t)i * 8);
    float4 a = p[0], b = p[1];
    uint4 o;
    o.x = pk2(a.x, a.y); o.y = pk2(a.z, a.w);
    o.z = pk2(b.x, b.y); o.w = pk2(b.z, b.w);
    *(uint4*)(xb + (size_t)i * 8) = o;
  } else if (gid < 5120) {
    int t = gid - 4096; trans64(wq, wqt, 2048, 2048, t & 31, t >> 5, tl);
  } else if (gid < 5376) {
    int t = gid - 5120; trans64(wk, wkvt, 2048, 512, t & 7, t >> 3, tl);
  } else if (gid < 5632) {
    int t = gid - 5376; trans64(wv, wkvt + 512 * 2048, 2048, 512, t & 7, t >> 3, tl);
  } else {
    int t = gid - 5632; trans64(wo, wot, 2048, 2048, t & 31, t >> 5, tl);
  }
}

// ---------------- GEMM: C = A[M][K] x BT[N][K], 128x128 tile, BK=64, 4 waves ----------------
// MODE 0: C f32 [4096][2048] (O projection). grid (16,32).
// MODE 3: fused QKV. grid (24,32): bx<16 -> Q: rms+rope*(log2e/sqrt(D)) -> bf16 Cout;
//         bx 16..19 -> K: rms+rope -> Kout; bx 20..23 -> V: bf16^T -> Vout (b,kvh,d,t).
// Both grids XCD-swizzled (nwg % 8 == 0, bijective).
template <int MODE>
__global__ __launch_bounds__(256) void k_gemm(
    const u16* __restrict__ A, const u16* __restrict__ BT0, const u16* __restrict__ BT1,
    void* __restrict__ Cout, u16* __restrict__ Kout, u16* __restrict__ Vout, int K,
    const float* __restrict__ nwq, const float* __restrict__ nwk,
    const float* __restrict__ fc, const float* __restrict__ fs) {
  constexpr int NX = (MODE == 0) ? 16 : 24;
  constexpr int NWG = NX * 32;
  __shared__ char lds[32768];
  char* As = lds; char* Bs = lds + 16384;
  int tid = threadIdx.x, w = tid >> 6, l = tid & 63, lg = l >> 4, ll = l & 15;
  // XCD-aware bijective remap
  int lid = blockIdx.y * NX + blockIdx.x;
  int nid = (lid & 7) * (NWG >> 3) + (lid >> 3);
  int bxt = nid % NX;
  int bm0 = (nid / NX) * 128;
  bool qpath = (MODE == 0) || (bxt < 16);
  const u16* BT = qpath ? BT0 : BT1;
  int bn0 = qpath ? bxt * 128 : (bxt - 16) * 128;
  int wr = w >> 1, wc = w & 1;
  f32x4 acc[4][4] = {};
  for (int k0 = 0; k0 < K; k0 += 64) {
#pragma unroll
    for (int i = 0; i < 4; i++) {
      int base = i * 256 + (w << 6);       // wave-uniform chunk base
      int p = base + l;                    // this lane's 16B chunk
      int r = p >> 3, kc = (p & 7) ^ (r & 7);  // pre-swizzled global source
      gll16(A + (size_t)(bm0 + r) * K + k0 + kc * 8, As + base * 16);
      gll16(BT + (size_t)(bn0 + r) * K + k0 + kc * 8, Bs + base * 16);
    }
    asm volatile("s_waitcnt vmcnt(0)" ::: "memory");
    __syncthreads();
#pragma unroll
    for (int ks = 0; ks < 2; ks++) {
      bf16x8 af[4], bfr[4];
#pragma unroll
      for (int m = 0; m < 4; m++) {
        int row = 64 * wr + 16 * m + ll;
        af[m] = *(const bf16x8*)(As + row * 128 + (((lg + 4 * ks) ^ (row & 7)) << 4));
      }
#pragma unroll
      for (int n = 0; n < 4; n++) {
        int row = 64 * wc + 16 * n + ll;
        bfr[n] = *(const bf16x8*)(Bs + row * 128 + (((lg + 4 * ks) ^ (row & 7)) << 4));
      }
#pragma unroll
      for (int m = 0; m < 4; m++)
#pragma unroll
        for (int n = 0; n < 4; n++)
          acc[m][n] = __builtin_amdgcn_mfma_f32_16x16x32_bf16(af[m], bfr[n], acc[m][n], 0, 0, 0);
    }
    __syncthreads();
  }

  if (MODE == 0) {
    float* C = (float*)Cout;
#pragma unroll
    for (int m = 0; m < 4; m++)
#pragma unroll
      for (int n = 0; n < 4; n++) {
        int row = bm0 + 64 * wr + 16 * m + 4 * lg;
        int col = bn0 + 64 * wc + 16 * n + ll;
        float* cp = C + (size_t)row * 2048 + col;
#pragma unroll
        for (int r = 0; r < 4; r++) cp[(size_t)r * 2048] = acc[m][n][r];
      }
    return;
  }

  if (qpath || bn0 < 512) {
    // --- fused RMSNorm + RoPE + bf16 store (Q or K heads); all-lane straight-line
    // epilogue (r9-proven; half-lane predicated version regressed 24us -- r10 lesson) ---
    const float* nw = qpath ? nwq : nwk;
    u16* O = qpath ? (u16*)Cout : Kout;
    int ostride = qpath ? 2048 : 512;
    // Q: log2e/sqrt(128) (exp2-domain attention); K: 1
    float outscale = qpath ? 0.12751744843f : 1.0f;
    float* ssum = (float*)lds;  // [wr][64 rows][wc]
    float ps[4][4];
#pragma unroll
    for (int m = 0; m < 4; m++)
#pragma unroll
      for (int r = 0; r < 4; r++) {
        float p = 0.f;
#pragma unroll
        for (int n = 0; n < 4; n++) p += acc[m][n][r] * acc[m][n][r];
#pragma unroll
        for (int msk = 1; msk < 16; msk <<= 1) p += __shfl_xor(p, msk);
        ps[m][r] = p;
      }
    if (ll == 0) {
#pragma unroll
      for (int m = 0; m < 4; m++)
#pragma unroll
        for (int r = 0; r < 4; r++)
          ssum[wr * 128 + (16 * m + 4 * lg + r) * 2 + wc] = ps[m][r];
    }
    __syncthreads();
    float rs[4][4];
#pragma unroll
    for (int m = 0; m < 4; m++)
#pragma unroll
      for (int r = 0; r < 4; r++) {
        int rowl = 16 * m + 4 * lg + r;
        float tot = ssum[wr * 128 + rowl * 2] + ssum[wr * 128 + rowl * 2 + 1];
        rs[m][r] = rsqrtf(tot * (1.0f / 128.0f) + 1e-5f) * outscale;
      }
#pragma unroll
    for (int m = 0; m < 4; m++)
#pragma unroll
      for (int n = 0; n < 4; n++) {
        int d = 64 * wc + 16 * n + ll;     // dim within head (0..127)
        float wgt = nw[d];
        int i = d >> 1;
#pragma unroll
        for (int r = 0; r < 4; r++) {
          int row = bm0 + 64 * wr + 16 * m + 4 * lg + r;
          int t = row & 2047;
          float y = acc[m][n][r] * rs[m][r] * wgt;
          float p = __shfl_xor(y, 1);
          float c = fc[t * 64 + i], s = fs[t * 64 + i];
          float o = (ll & 1) ? (p * s + y * c) : (y * c - p * s);
          O[(size_t)row * ostride + bn0 + d] = f2bf(o);
        }
      }
  } else {
    // --- V: bf16 + transpose to (b,kvh,d,t) via swizzled LDS ---
    int b = bm0 >> 11, t0g = bm0 & 2047;
    int kvh = (bn0 - 512) >> 7;
    int bk = b * 4 + kvh;
#pragma unroll
    for (int m = 0; m < 4; m++)
#pragma unroll
      for (int n = 0; n < 4; n++) {
        int d = 64 * wc + 16 * n + ll;
        int tloc = 64 * wr + 16 * m + 4 * lg;
        u32 w0 = pk2(acc[m][n][0], acc[m][n][1]);
        u32 w1 = pk2(acc[m][n][2], acc[m][n][3]);
        int byte = (d * 256 + tloc * 2) ^ ((d & 7) << 4);
        *(uint2*)(lds + byte) = make_uint2(w0, w1);
      }
    __syncthreads();
    int tc = tid & 15, dbase = tid >> 4;
#pragma unroll
    for (int pass = 0; pass < 8; pass++) {
      int d = dbase + pass * 16;
      int byte = (d * 256 + tc * 16) ^ ((d & 7) << 4);
      uint4 v = *(const uint4*)(lds + byte);
      *(uint4*)(Vout + ((size_t)(bk * 128 + d)) * 2048 + t0g + tc * 8) = v;
    }
  }
}

// ---------------- causal GQA flash attention (KVBLK=64, V direct from L2) ----------------
// 1024 blocks, one 64-row q-tile each, heavy (qb=31) first; fid&7 -> (b,kvh) so each
// XCD's L2 holds its 0.5MB V^T + 0.5MB K slice. K double-buffered in LDS via
// global_load_lds (pre-swizzled source, proven pipeline); V fragments read DIRECTLY
// from global (L2-resident, per-lane 16B) -- no V staging, no V bank conflicts.
// LDS = K dbuf 32K + P 8K = 40KB -> 3 blocks/CU (12 waves: drain cover, r11 diagnosis).
// exp2-domain softmax, defer-max THR=11.5, ones-MFMA row-sum, setprio.
// __launch_bounds__(256,4) caps VGPR 128 (r6/r8 lesson).
__global__ __launch_bounds__(256, 4) void k_attn(
    const u16* __restrict__ Q, const u16* __restrict__ Kb,
    const u16* __restrict__ Vt, u16* __restrict__ Y) {
  __shared__ char lds[40960];  // K0 16K | K1 16K | P 8K
  char* Ps = lds + 32768;
  int tid = threadIdx.x, w = tid >> 6, l = tid & 63, lg = l >> 4, ll = l & 15;
  int fid = blockIdx.x;
  int g = fid & 7, rank = fid >> 3;   // rank 0..127
  int b = g >> 2, kvh = g & 3;
  int h = kvh * 4 + (rank & 3);
  int qb = 31 - (rank >> 2);          // heavy q-tiles dispatched first
  int q0 = qb * 64;
  const u16* Kbase = Kb + ((size_t)b * 2048) * 512 + kvh * 128;
  const u16* Vbase = Vt + ((size_t)(b * 4 + kvh) * 128) * 2048;

  const bf16x8 vones = {(short)0x3F80, (short)0x3F80, (short)0x3F80, (short)0x3F80,
                        (short)0x3F80, (short)0x3F80, (short)0x3F80, (short)0x3F80};

  bf16x8 qf[4];
  {
    int qrow = b * 2048 + q0 + 16 * w + ll;
    const u16* qp = Q + (size_t)qrow * 2048 + h * 128;
#pragma unroll
    for (int ks = 0; ks < 4; ks++) qf[ks] = *(const bf16x8*)(qp + ks * 32 + lg * 8);
  }
  f32x4 o[8] = {};
  f32x4 lacc = {};
  float mrow[4];
#pragma unroll
  for (int r = 0; r < 4; r++) mrow[r] = -1e30f;

  auto stage = [&](int bi, int k0) {  // K tile [64][128] only
    char* Kd = lds + bi * 16384;
#pragma unroll
    for (int i = 0; i < 4; i++) {
      int c = i * 256 + tid;
      int dst = (i * 256 + (w << 6)) * 16;  // wave-uniform chunk base * 16B
      int krow = c >> 4, ksrc = (c & 15) ^ (krow & 7);
      gll16(Kbase + (size_t)(k0 + krow) * 512 + ksrc * 8, Kd + dst);
    }
  };

  stage(0, 0);
  asm volatile("s_waitcnt vmcnt(0)" ::: "memory");
  __syncthreads();

  int cur = 0;
  for (int it = 0; it <= qb; ++it) {
    if (it < qb) stage(cur ^ 1, (it + 1) * 64);  // async prefetch next K tile
    char* Ks = lds + cur * 16384;
    int k0 = it * 64;
    // S = Q K^T (per wave: 16 q-rows x 64 kv); log2e/sqrt(D) pre-folded into Q
    f32x4 s[4] = {};
    __builtin_amdgcn_s_setprio(1);
#pragma unroll
    for (int ks = 0; ks < 4; ks++) {
#pragma unroll
      for (int n = 0; n < 4; n++) {
        int row = 16 * n + ll;
        bf16x8 kf = *(const bf16x8*)(Ks + ((row * 256 + (lg + 4 * ks) * 16) ^ ((row & 7) << 4)));
        s[n] = __builtin_amdgcn_mfma_f32_16x16x32_bf16(qf[ks], kf, s[n], 0, 0, 0);
      }
    }
    __builtin_amdgcn_s_setprio(0);
    if (it == qb) {  // diagonal tile: causal mask
#pragma unroll
      for (int n = 0; n < 4; n++) {
        int kk = k0 + 16 * n + ll;
#pragma unroll
        for (int r = 0; r < 4; r++) {
          int qq = q0 + 16 * w + 4 * lg + r;
          if (kk > qq) s[n][r] = -1e30f;
        }
      }
    }
    // online softmax, exp2 domain (C layout: row = 4*lg + r, col = ll)
    float pmax[4];
#pragma unroll
    for (int r = 0; r < 4; r++) {
      float mx = fmaxf(fmaxf(s[0][r], s[1][r]), fmaxf(s[2][r], s[3][r]));
#pragma unroll
      for (int m = 1; m < 16; m <<= 1) mx = fmaxf(mx, __shfl_xor(mx, m));
      pmax[r] = mx;
    }
    float dmax = fmaxf(fmaxf(pmax[0] - mrow[0], pmax[1] - mrow[1]),
                       fmaxf(pmax[2] - mrow[2], pmax[3] - mrow[3]));
    if (__any(dmax > 11.5f)) {  // defer-max (log2 units; P bounded by 2^11.5)
#pragma unroll
      for (int r = 0; r < 4; r++) {
        float mn = fmaxf(mrow[r], pmax[r]);
        float al = exp2f(mrow[r] - mn);
        mrow[r] = mn;
        lacc[r] *= al;
#pragma unroll
        for (int n = 0; n < 8; n++) o[n][r] *= al;
      }
    }
    // exp2 + P (bf16) -> per-wave swizzled LDS tile (wave-local ds order)
#pragma unroll
    for (int r = 0; r < 4; r++) {
      int prow = 4 * lg + r;
#pragma unroll
      for (int n = 0; n < 4; n++) {
        float e = exp2f(s[n][r] - mrow[r]);
        int byte = (w << 11) + ((prow * 128 + (16 * n + ll) * 2) ^ ((prow & 7) << 4));
        *(u16*)(Ps + byte) = f2bf_fast(e);
      }
    }
    // O += P V ; l += P 1. V fragments direct from global (L2-resident, XCD-local).
    __builtin_amdgcn_s_setprio(1);
#pragma unroll
    for (int ks = 0; ks < 2; ks++) {
      bf16x8 pf = *(const bf16x8*)(Ps + (w << 11) + ((ll * 128 + (lg + 4 * ks) * 16) ^ ((ll & 7) << 4)));
      lacc = __builtin_amdgcn_mfma_f32_16x16x32_bf16(pf, vones, lacc, 0, 0, 0);
#pragma unroll
      for (int n = 0; n < 8; n++) {
        int row = 16 * n + ll;
        bf16x8 vf = *(const bf16x8*)(Vt + ((size_t)(b * 4 + kvh) * 128 + row) * 2048 + k0 + (lg + 4 * ks) * 8);
        o[n] = __builtin_amdgcn_mfma_f32_16x16x32_bf16(pf, vf, o[n], 0, 0, 0);
      }
    }
    __builtin_amdgcn_s_setprio(0);
    // drain K prefetch, publish to all waves
    asm volatile("s_waitcnt vmcnt(0)" ::: "memory");
    __syncthreads();
    cur ^= 1;
  }
  // output
  float rl[4];
#pragma unroll
  for (int r = 0; r < 4; r++) rl[r] = 1.0f / lacc[r];
#pragma unroll
  for (int n = 0; n < 8; n++) {
    int col = h * 128 + 16 * n + ll;
#pragma unroll
    for (int r = 0; r < 4; r++) {
      int trow = b * 2048 + q0 + 16 * w + 4 * lg + r;
      Y[(size_t)trow * 2048 + col] = f2bf_fast(o[n][r] * rl[r]);
    }
  }
  (void)Vbase;
}

extern "C" void kernel_launch(void* const* d_in, const int* in_sizes, int n_in,
                              void* d_out, int out_size, void* d_ws, size_t ws_size,
                              hipStream_t stream) {
  const float* x   = (const float*)d_in[0];
  const float* fc  = (const float*)d_in[1];
  const float* fs  = (const float*)d_in[2];
  const float* wq  = (const float*)d_in[3];
  const float* wk  = (const float*)d_in[4];
  const float* wv  = (const float*)d_in[5];
  const float* wo  = (const float*)d_in[6];
  const float* qnw = (const float*)d_in[7];
  const float* knw = (const float*)d_in[8];
  float* out = (float*)d_out;

  const size_t MB = 1ull << 20;
  char* ws = (char*)d_ws;
  u16* xb   = (u16*)(ws);             // 16 MB  x bf16
  u16* wqt  = (u16*)(ws + 16 * MB);   //  8 MB  wq^T bf16 [2048][2048]
  u16* wkvt = (u16*)(ws + 24 * MB);   //  4 MB  [wk^T;wv^T] bf16 [1024][2048]
  u16* wot  = (u16*)(ws + 28 * MB);   //  8 MB  wo^T bf16
  u16* Qb   = (u16*)(ws + 36 * MB);   // 16 MB  Q' bf16 (rms+rope, x log2e/sqrt(D))
  u16* Kbq  = (u16*)(ws + 52 * MB);   //  4 MB  K' bf16 (rms+rope)
  u16* Vtg  = (u16*)(ws + 56 * MB);   //  4 MB  V^T bf16 (b,kvh,d,t)
  u16* Yb   = (u16*)(ws + 60 * MB);   // 16 MB  attn out bf16

  hipLaunchKernelGGL(k_prep, dim3(6656), dim3(256), 0, stream,
                     x, xb, wq, wqt, wk, wv, wkvt, wo, wot);
  // fused QKV projection: Q (rms+rope+log2e-scale), K (rms+rope), V (transpose)
  hipLaunchKernelGGL((k_gemm<3>), dim3(24, 32), dim3(256), 0, stream,
                     xb, wqt, wkvt, (void*)Qb, Kbq, Vtg, 2048,
                     qnw, knw, fc, fs);
  hipLaunchKernelGGL(k_attn, dim3(1024), dim3(256), 0, stream, Qb, Kbq, Vtg, Yb);
  hipLaunchKernelGGL((k_gemm<0>), dim3(16, 32), dim3(256), 0, stream,
                     Yb, wot, (const u16*)nullptr, (void*)out, (u16*)nullptr, (u16*)nullptr, 2048,
                     nullptr, nullptr, nullptr, nullptr);
}

// Round 14
// 234.071 us; speedup vs baseline: 1.6626x; 1.6626x over previous
//
#include <hip/hip_runtime.h>
#include <hip/hip_bf16.h>

using u16 = unsigned short;
using u32 = unsigned int;

typedef short bf16x8 __attribute__((ext_vector_type(8)));
typedef float f32x4 __attribute__((ext_vector_type(4)));

#define AS1 __attribute__((address_space(1)))
#define AS3 __attribute__((address_space(3)))

__device__ __forceinline__ void gll16(const void* g, void* l) {
  __builtin_amdgcn_global_load_lds((const AS1 u32*)g, (AS3 u32*)l, 16, 0, 0);
}

__device__ __forceinline__ u16 f2bf(float x) {  // round-to-nearest-even bf16
  u32 u = __builtin_bit_cast(u32, x);
  u32 r = (u + 0x7fffu + ((u >> 16) & 1u)) >> 16;
  return (u16)r;
}
__device__ __forceinline__ u32 pk2(float lo, float hi) {
  return (u32)f2bf(lo) | ((u32)f2bf(hi) << 16);
}
__device__ __forceinline__ u16 f2bf_fast(float x) {  // hw cvt (validated r5/r6)
  __hip_bfloat16 h = __float2bfloat16(x);
  return __builtin_bit_cast(u16, h);
}

// ---------------- merged prep: x cast (blocks 0..4095) + 4 weight transposes ----------------
__device__ __forceinline__ void trans64(const float* __restrict__ in, u16* __restrict__ out,
                                        int R, int Cc, int bx, int by, float (*tl)[65]) {
  int c0 = bx * 64, r0 = by * 64, tid = threadIdx.x;
#pragma unroll
  for (int i = 0; i < 16; i++) {
    int idx = i * 256 + tid; int tr = idx >> 6, tc = idx & 63;
    tl[tr][tc] = in[(size_t)(r0 + tr) * Cc + c0 + tc];
  }
  __syncthreads();
#pragma unroll
  for (int i = 0; i < 16; i++) {
    int idx = i * 256 + tid; int tr = idx >> 6, tc = idx & 63;
    out[(size_t)(c0 + tr) * R + r0 + tc] = f2bf(tl[tc][tr]);
  }
}

__global__ void k_prep(const float* __restrict__ x, u16* __restrict__ xb,
                       const float* __restrict__ wq, u16* __restrict__ wqt,
                       const float* __restrict__ wk, const float* __restrict__ wv,
                       u16* __restrict__ wkvt,
                       const float* __restrict__ wo, u16* __restrict__ wot) {
  __shared__ float tl[64][65];
  int gid = blockIdx.x;
  if (gid < 4096) {
    int i = gid * 256 + threadIdx.x;
    const float4* p = (const float4*)(x + (size_t)i * 8);
    float4 a = p[0], b = p[1];
    uint4 o;
    o.x = pk2(a.x, a.y); o.y = pk2(a.z, a.w);
    o.z = pk2(b.x, b.y); o.w = pk2(b.z, b.w);
    *(uint4*)(xb + (size_t)i * 8) = o;
  } else if (gid < 5120) {
    int t = gid - 4096; trans64(wq, wqt, 2048, 2048, t & 31, t >> 5, tl);
  } else if (gid < 5376) {
    int t = gid - 5120; trans64(wk, wkvt, 2048, 512, t & 7, t >> 3, tl);
  } else if (gid < 5632) {
    int t = gid - 5376; trans64(wv, wkvt + 512 * 2048, 2048, 512, t & 7, t >> 3, tl);
  } else {
    int t = gid - 5632; trans64(wo, wot, 2048, 2048, t & 31, t >> 5, tl);
  }
}

// ---------------- GEMM: C = A[M][K] x BT[N][K], 128x128 tile, BK=64, 4 waves ----------------
// MODE 0: C f32 [4096][2048] (O projection). grid (16,32).
// MODE 3: fused QKV. grid (24,32): bx<16 -> Q: rms+rope*(log2e/sqrt(D)) -> bf16 Cout;
//         bx 16..19 -> K: rms+rope -> Kout; bx 20..23 -> V: bf16^T -> Vout (b,kvh,d,t).
// XCD remap: each XCD owns a RECTANGLE of tiles (12bxt x 8bm for MODE3, 8x8 for MODE0)
// so its L2 working set is A-rows + few B-panels (~10MB) instead of all B (r13 change).
template <int MODE>
__global__ __launch_bounds__(256) void k_gemm(
    const u16* __restrict__ A, const u16* __restrict__ BT0, const u16* __restrict__ BT1,
    void* __restrict__ Cout, u16* __restrict__ Kout, u16* __restrict__ Vout, int K,
    const float* __restrict__ nwq, const float* __restrict__ nwk,
    const float* __restrict__ fc, const float* __restrict__ fs) {
  constexpr int NX = (MODE == 0) ? 16 : 24;
  constexpr int RBX = (MODE == 0) ? 8 : 12;   // rectangle width (bxt per XCD)
  __shared__ char lds[32768];
  char* As = lds; char* Bs = lds + 16384;
  int tid = threadIdx.x, w = tid >> 6, l = tid & 63, lg = l >> 4, ll = l & 15;
  // XCD rectangle remap (bijective): xcd = lid&7; 2 col-groups x 4 row-groups
  int lid = blockIdx.y * NX + blockIdx.x;
  int xcd = lid & 7, r = lid >> 3;            // r in 0..NWG/8-1
  int colg = xcd & 1, rowg = xcd >> 1;
  int bxt = colg * RBX + r % RBX;
  int bm0 = (rowg * 8 + r / RBX) * 128;
  bool qpath = (MODE == 0) || (bxt < 16);
  const u16* BT = qpath ? BT0 : BT1;
  int bn0 = qpath ? bxt * 128 : (bxt - 16) * 128;
  int wr = w >> 1, wc = w & 1;
  f32x4 acc[4][4] = {};
  for (int k0 = 0; k0 < K; k0 += 64) {
#pragma unroll
    for (int i = 0; i < 4; i++) {
      int base = i * 256 + (w << 6);       // wave-uniform chunk base
      int p = base + l;                    // this lane's 16B chunk
      int rr = p >> 3, kc = (p & 7) ^ (rr & 7);  // pre-swizzled global source
      gll16(A + (size_t)(bm0 + rr) * K + k0 + kc * 8, As + base * 16);
      gll16(BT + (size_t)(bn0 + rr) * K + k0 + kc * 8, Bs + base * 16);
    }
    asm volatile("s_waitcnt vmcnt(0)" ::: "memory");
    __syncthreads();
#pragma unroll
    for (int ks = 0; ks < 2; ks++) {
      bf16x8 af[4], bfr[4];
#pragma unroll
      for (int m = 0; m < 4; m++) {
        int row = 64 * wr + 16 * m + ll;
        af[m] = *(const bf16x8*)(As + row * 128 + (((lg + 4 * ks) ^ (row & 7)) << 4));
      }
#pragma unroll
      for (int n = 0; n < 4; n++) {
        int row = 64 * wc + 16 * n + ll;
        bfr[n] = *(const bf16x8*)(Bs + row * 128 + (((lg + 4 * ks) ^ (row & 7)) << 4));
      }
#pragma unroll
      for (int m = 0; m < 4; m++)
#pragma unroll
        for (int n = 0; n < 4; n++)
          acc[m][n] = __builtin_amdgcn_mfma_f32_16x16x32_bf16(af[m], bfr[n], acc[m][n], 0, 0, 0);
    }
    __syncthreads();
  }

  if (MODE == 0) {
    float* C = (float*)Cout;
#pragma unroll
    for (int m = 0; m < 4; m++)
#pragma unroll
      for (int n = 0; n < 4; n++) {
        int row = bm0 + 64 * wr + 16 * m + 4 * lg;
        int col = bn0 + 64 * wc + 16 * n + ll;
        float* cp = C + (size_t)row * 2048 + col;
#pragma unroll
        for (int r2 = 0; r2 < 4; r2++) cp[(size_t)r2 * 2048] = acc[m][n][r2];
      }
    return;
  }

  if (qpath || bn0 < 512) {
    // --- fused RMSNorm + RoPE + bf16 store (Q or K heads); all-lane straight-line
    // epilogue (r9-proven; half-lane predicated version regressed 24us -- r10 lesson) ---
    const float* nw = qpath ? nwq : nwk;
    u16* O = qpath ? (u16*)Cout : Kout;
    int ostride = qpath ? 2048 : 512;
    // Q: log2e/sqrt(128) (exp2-domain attention); K: 1
    float outscale = qpath ? 0.12751744843f : 1.0f;
    float* ssum = (float*)lds;  // [wr][64 rows][wc]
    float ps[4][4];
#pragma unroll
    for (int m = 0; m < 4; m++)
#pragma unroll
      for (int r2 = 0; r2 < 4; r2++) {
        float p = 0.f;
#pragma unroll
        for (int n = 0; n < 4; n++) p += acc[m][n][r2] * acc[m][n][r2];
#pragma unroll
        for (int msk = 1; msk < 16; msk <<= 1) p += __shfl_xor(p, msk);
        ps[m][r2] = p;
      }
    if (ll == 0) {
#pragma unroll
      for (int m = 0; m < 4; m++)
#pragma unroll
        for (int r2 = 0; r2 < 4; r2++)
          ssum[wr * 128 + (16 * m + 4 * lg + r2) * 2 + wc] = ps[m][r2];
    }
    __syncthreads();
    float rs[4][4];
#pragma unroll
    for (int m = 0; m < 4; m++)
#pragma unroll
      for (int r2 = 0; r2 < 4; r2++) {
        int rowl = 16 * m + 4 * lg + r2;
        float tot = ssum[wr * 128 + rowl * 2] + ssum[wr * 128 + rowl * 2 + 1];
        rs[m][r2] = rsqrtf(tot * (1.0f / 128.0f) + 1e-5f) * outscale;
      }
#pragma unroll
    for (int m = 0; m < 4; m++)
#pragma unroll
      for (int n = 0; n < 4; n++) {
        int d = 64 * wc + 16 * n + ll;     // dim within head (0..127)
        float wgt = nw[d];
        int i = d >> 1;
#pragma unroll
        for (int r2 = 0; r2 < 4; r2++) {
          int row = bm0 + 64 * wr + 16 * m + 4 * lg + r2;
          int t = row & 2047;
          float y = acc[m][n][r2] * rs[m][r2] * wgt;
          float p = __shfl_xor(y, 1);
          float c = fc[t * 64 + i], s = fs[t * 64 + i];
          float o = (ll & 1) ? (p * s + y * c) : (y * c - p * s);
          O[(size_t)row * ostride + bn0 + d] = f2bf(o);
        }
      }
  } else {
    // --- V: bf16 + transpose to (b,kvh,d,t) via swizzled LDS ---
    int b = bm0 >> 11, t0g = bm0 & 2047;
    int kvh = (bn0 - 512) >> 7;
    int bk = b * 4 + kvh;
#pragma unroll
    for (int m = 0; m < 4; m++)
#pragma unroll
      for (int n = 0; n < 4; n++) {
        int d = 64 * wc + 16 * n + ll;
        int tloc = 64 * wr + 16 * m + 4 * lg;
        u32 w0 = pk2(acc[m][n][0], acc[m][n][1]);
        u32 w1 = pk2(acc[m][n][2], acc[m][n][3]);
        int byte = (d * 256 + tloc * 2) ^ ((d & 7) << 4);
        *(uint2*)(lds + byte) = make_uint2(w0, w1);
      }
    __syncthreads();
    int tc = tid & 15, dbase = tid >> 4;
#pragma unroll
    for (int pass = 0; pass < 8; pass++) {
      int d = dbase + pass * 16;
      int byte = (d * 256 + tc * 16) ^ ((d & 7) << 4);
      uint4 v = *(const uint4*)(lds + byte);
      *(uint4*)(Vout + ((size_t)(bk * 128 + d)) * 2048 + t0g + tc * 8) = v;
    }
  }
}

// ---------------- causal GQA flash attention (r11-proven body, verbatim) ----------------
// 512 blocks: fid&7 -> (b,kvh) so each XCD's L2 holds one KV slice (1MB) + Q slice (2MB);
// 64 blocks/XCD = 2/CU exactly. Block handles q-tiles {pairId, 31-pairId} (uniform 33 iters).
// K/V double-buffered via global_load_lds w/ pre-swizzled source. exp2-domain softmax,
// defer-max THR=11.5, ones-MFMA row-sum, setprio. __launch_bounds__(256,4) caps VGPR 128.
// NOTE r12/r13 lessons: KVBLK=32 doubles per-iter overhead + V-row bank conflicts;
// V-from-L2 serializes against the in-order vmcnt prefetch queue. Do not repeat.
__global__ __launch_bounds__(256, 4) void k_attn(
    const u16* __restrict__ Q, const u16* __restrict__ Kb,
    const u16* __restrict__ Vt, u16* __restrict__ Y) {
  __shared__ char lds[73728];  // K0 16K | V0 16K | K1 16K | V1 16K | P 8K
  char* Ps = lds + 65536;
  int tid = threadIdx.x, w = tid >> 6, l = tid & 63, lg = l >> 4, ll = l & 15;
  int fid = blockIdx.x;
  int g = fid & 7, rank = fid >> 3;
  int b = g >> 2, kvh = g & 3;
  int h = kvh * 4 + (rank & 3);
  int pairId = rank >> 2;  // 0..15
  const u16* Kbase = Kb + ((size_t)b * 2048) * 512 + kvh * 128;
  const u16* Vbase = Vt + ((size_t)(b * 4 + kvh) * 128) * 2048;

  const bf16x8 vones = {(short)0x3F80, (short)0x3F80, (short)0x3F80, (short)0x3F80,
                        (short)0x3F80, (short)0x3F80, (short)0x3F80, (short)0x3F80};

#pragma unroll 1
  for (int qi = 0; qi < 2; qi++) {
    int qb = qi ? (31 - pairId) : pairId;
    int q0 = qb * 64;
    bf16x8 qf[4];
    {
      int qrow = b * 2048 + q0 + 16 * w + ll;
      const u16* qp = Q + (size_t)qrow * 2048 + h * 128;
#pragma unroll
      for (int ks = 0; ks < 4; ks++) qf[ks] = *(const bf16x8*)(qp + ks * 32 + lg * 8);
    }
    f32x4 o[8] = {};
    f32x4 lacc = {};
    float mrow[4];
#pragma unroll
    for (int r = 0; r < 4; r++) mrow[r] = -1e30f;

    auto stage = [&](int bi, int k0) {
      char* Kd = lds + (bi ? 32768 : 0);
      char* Vd = lds + (bi ? 49152 : 16384);
#pragma unroll
      for (int i = 0; i < 4; i++) {
        int c = i * 256 + tid;
        int dst = (i * 256 + (w << 6)) * 16;  // wave-uniform chunk base * 16B
        int krow = c >> 4, ksrc = (c & 15) ^ (krow & 7);
        gll16(Kbase + (size_t)(k0 + krow) * 512 + ksrc * 8, Kd + dst);
        int vd = c >> 3, vsrc = (c & 7) ^ (vd & 7);
        gll16(Vbase + (size_t)vd * 2048 + k0 + vsrc * 8, Vd + dst);
      }
    };

    stage(0, 0);
    asm volatile("s_waitcnt vmcnt(0)" ::: "memory");
    __syncthreads();

    int cur = 0;
    for (int it = 0; it <= qb; ++it) {
      if (it < qb) stage(cur ^ 1, (it + 1) * 64);  // async prefetch next tile
      char* Ks = lds + (cur ? 32768 : 0);
      char* Vs = lds + (cur ? 49152 : 16384);
      // S = Q K^T (per wave: 16 q-rows x 64 kv); log2e/sqrt(D) pre-folded into Q
      f32x4 s[4] = {};
      __builtin_amdgcn_s_setprio(1);
#pragma unroll
      for (int ks = 0; ks < 4; ks++) {
#pragma unroll
        for (int n = 0; n < 4; n++) {
          int row = 16 * n + ll;
          bf16x8 kf = *(const bf16x8*)(Ks + ((row * 256 + (lg + 4 * ks) * 16) ^ ((row & 7) << 4)));
          s[n] = __builtin_amdgcn_mfma_f32_16x16x32_bf16(qf[ks], kf, s[n], 0, 0, 0);
        }
      }
      __builtin_amdgcn_s_setprio(0);
      if (it == qb) {  // diagonal tile: causal mask
        int k0 = it * 64;
#pragma unroll
        for (int n = 0; n < 4; n++) {
          int kk = k0 + 16 * n + ll;
#pragma unroll
          for (int r = 0; r < 4; r++) {
            int qq = q0 + 16 * w + 4 * lg + r;
            if (kk > qq) s[n][r] = -1e30f;
          }
        }
      }
      // online softmax, exp2 domain (C layout: row = 4*lg + r, col = ll)
      float pmax[4];
#pragma unroll
      for (int r = 0; r < 4; r++) {
        float mx = fmaxf(fmaxf(s[0][r], s[1][r]), fmaxf(s[2][r], s[3][r]));
#pragma unroll
        for (int m = 1; m < 16; m <<= 1) mx = fmaxf(mx, __shfl_xor(mx, m));
        pmax[r] = mx;
      }
      float dmax = fmaxf(fmaxf(pmax[0] - mrow[0], pmax[1] - mrow[1]),
                         fmaxf(pmax[2] - mrow[2], pmax[3] - mrow[3]));
      if (__any(dmax > 11.5f)) {  // defer-max (log2 units; P bounded by 2^11.5)
#pragma unroll
        for (int r = 0; r < 4; r++) {
          float mn = fmaxf(mrow[r], pmax[r]);
          float al = exp2f(mrow[r] - mn);
          mrow[r] = mn;
          lacc[r] *= al;
#pragma unroll
          for (int n = 0; n < 8; n++) o[n][r] *= al;
        }
      }
      // exp2 + P (bf16) -> per-wave swizzled LDS tile (wave-local ds order)
#pragma unroll
      for (int r = 0; r < 4; r++) {
        int prow = 4 * lg + r;
#pragma unroll
        for (int n = 0; n < 4; n++) {
          float e = exp2f(s[n][r] - mrow[r]);
          int byte = (w << 11) + ((prow * 128 + (16 * n + ll) * 2) ^ ((prow & 7) << 4));
          *(u16*)(Ps + byte) = f2bf_fast(e);
        }
      }
      // O += P V ; l += P 1 (row-sum on the MFMA pipe)
      __builtin_amdgcn_s_setprio(1);
#pragma unroll
      for (int ks = 0; ks < 2; ks++) {
        bf16x8 pf = *(const bf16x8*)(Ps + (w << 11) + ((ll * 128 + (lg + 4 * ks) * 16) ^ ((ll & 7) << 4)));
        lacc = __builtin_amdgcn_mfma_f32_16x16x32_bf16(pf, vones, lacc, 0, 0, 0);
#pragma unroll
        for (int n = 0; n < 8; n++) {
          int row = 16 * n + ll;
          bf16x8 vf = *(const bf16x8*)(Vs + ((row * 128 + (lg + 4 * ks) * 16) ^ ((row & 7) << 4)));
          o[n] = __builtin_amdgcn_mfma_f32_16x16x32_bf16(pf, vf, o[n], 0, 0, 0);
        }
      }
      __builtin_amdgcn_s_setprio(0);
      // drain this iteration's prefetch, publish to all waves
      asm volatile("s_waitcnt vmcnt(0)" ::: "memory");
      __syncthreads();
      cur ^= 1;
    }
    // output
    float rl[4];
#pragma unroll
    for (int r = 0; r < 4; r++) rl[r] = 1.0f / lacc[r];
#pragma unroll
    for (int n = 0; n < 8; n++) {
      int col = h * 128 + 16 * n + ll;
#pragma unroll
      for (int r = 0; r < 4; r++) {
        int trow = b * 2048 + q0 + 16 * w + 4 * lg + r;
        Y[(size_t)trow * 2048 + col] = f2bf_fast(o[n][r] * rl[r]);
      }
    }
  }
}

extern "C" void kernel_launch(void* const* d_in, const int* in_sizes, int n_in,
                              void* d_out, int out_size, void* d_ws, size_t ws_size,
                              hipStream_t stream) {
  const float* x   = (const float*)d_in[0];
  const float* fc  = (const float*)d_in[1];
  const float* fs  = (const float*)d_in[2];
  const float* wq  = (const float*)d_in[3];
  const float* wk  = (const float*)d_in[4];
  const float* wv  = (const float*)d_in[5];
  const float* wo  = (const float*)d_in[6];
  const float* qnw = (const float*)d_in[7];
  const float* knw = (const float*)d_in[8];
  float* out = (float*)d_out;

  const size_t MB = 1ull << 20;
  char* ws = (char*)d_ws;
  u16* xb   = (u16*)(ws);             // 16 MB  x bf16
  u16* wqt  = (u16*)(ws + 16 * MB);   //  8 MB  wq^T bf16 [2048][2048]
  u16* wkvt = (u16*)(ws + 24 * MB);   //  4 MB  [wk^T;wv^T] bf16 [1024][2048]
  u16* wot  = (u16*)(ws + 28 * MB);   //  8 MB  wo^T bf16
  u16* Qb   = (u16*)(ws + 36 * MB);   // 16 MB  Q' bf16 (rms+rope, x log2e/sqrt(D))
  u16* Kbq  = (u16*)(ws + 52 * MB);   //  4 MB  K' bf16 (rms+rope)
  u16* Vtg  = (u16*)(ws + 56 * MB);   //  4 MB  V^T bf16 (b,kvh,d,t)
  u16* Yb   = (u16*)(ws + 60 * MB);   // 16 MB  attn out bf16

  hipLaunchKernelGGL(k_prep, dim3(6656), dim3(256), 0, stream,
                     x, xb, wq, wqt, wk, wv, wkvt, wo, wot);
  // fused QKV projection: Q (rms+rope+log2e-scale), K (rms+rope), V (transpose)
  hipLaunchKernelGGL((k_gemm<3>), dim3(24, 32), dim3(256), 0, stream,
                     xb, wqt, wkvt, (void*)Qb, Kbq, Vtg, 2048,
                     qnw, knw, fc, fs);
  hipLaunchKernelGGL(k_attn, dim3(512), dim3(256), 0, stream, Qb, Kbq, Vtg, Yb);
  hipLaunchKernelGGL((k_gemm<0>), dim3(16, 32), dim3(256), 0, stream,
                     Yb, wot, (const u16*)nullptr, (void*)out, (u16*)nullptr, (u16*)nullptr, 2048,
                     nullptr, nullptr, nullptr, nullptr);
}

// Round 15
// 216.030 us; speedup vs baseline: 1.8015x; 1.0835x over previous
//
#include <hip/hip_runtime.h>
#include <hip/hip_bf16.h>

using u16 = unsigned short;
using u32 = unsigned int;

typedef short bf16x8 __attribute__((ext_vector_type(8)));
typedef float f32x4 __attribute__((ext_vector_type(4)));

#define AS1 __attribute__((address_space(1)))
#define AS3 __attribute__((address_space(3)))

__device__ __forceinline__ void gll16(const void* g, void* l) {
  __builtin_amdgcn_global_load_lds((const AS1 u32*)g, (AS3 u32*)l, 16, 0, 0);
}

__device__ __forceinline__ u16 f2bf(float x) {  // round-to-nearest-even bf16
  u32 u = __builtin_bit_cast(u32, x);
  u32 r = (u + 0x7fffu + ((u >> 16) & 1u)) >> 16;
  return (u16)r;
}
__device__ __forceinline__ u32 pk2(float lo, float hi) {
  return (u32)f2bf(lo) | ((u32)f2bf(hi) << 16);
}
__device__ __forceinline__ u16 f2bf_fast(float x) {  // hw cvt (validated r5/r6)
  __hip_bfloat16 h = __float2bfloat16(x);
  return __builtin_bit_cast(u16, h);
}

// ---------------- merged prep: x cast + 4 weight transposes + fused cos/sin table ----------------
__device__ __forceinline__ void trans64(const float* __restrict__ in, u16* __restrict__ out,
                                        int R, int Cc, int bx, int by, float (*tl)[65]) {
  int c0 = bx * 64, r0 = by * 64, tid = threadIdx.x;
#pragma unroll
  for (int i = 0; i < 16; i++) {
    int idx = i * 256 + tid; int tr = idx >> 6, tc = idx & 63;
    tl[tr][tc] = in[(size_t)(r0 + tr) * Cc + c0 + tc];
  }
  __syncthreads();
#pragma unroll
  for (int i = 0; i < 16; i++) {
    int idx = i * 256 + tid; int tr = idx >> 6, tc = idx & 63;
    out[(size_t)(c0 + tr) * R + r0 + tc] = f2bf(tl[tc][tr]);
  }
}

__global__ void k_prep(const float* __restrict__ x, u16* __restrict__ xb,
                       const float* __restrict__ wq, u16* __restrict__ wqt,
                       const float* __restrict__ wk, const float* __restrict__ wv,
                       u16* __restrict__ wkvt,
                       const float* __restrict__ wo, u16* __restrict__ wot,
                       const float* __restrict__ fc, const float* __restrict__ fs,
                       float2* __restrict__ fcs) {
  __shared__ float tl[64][65];
  int gid = blockIdx.x;
  if (gid < 4096) {
    int i = gid * 256 + threadIdx.x;
    const float4* p = (const float4*)(x + (size_t)i * 8);
    float4 a = p[0], b = p[1];
    uint4 o;
    o.x = pk2(a.x, a.y); o.y = pk2(a.z, a.w);
    o.z = pk2(b.x, b.y); o.w = pk2(b.z, b.w);
    *(uint4*)(xb + (size_t)i * 8) = o;
  } else if (gid < 5120) {
    int t = gid - 4096; trans64(wq, wqt, 2048, 2048, t & 31, t >> 5, tl);
  } else if (gid < 5376) {
    int t = gid - 5120; trans64(wk, wkvt, 2048, 512, t & 7, t >> 3, tl);
  } else if (gid < 5632) {
    int t = gid - 5376; trans64(wv, wkvt + 512 * 2048, 2048, 512, t & 7, t >> 3, tl);
  } else if (gid < 6656) {
    int t = gid - 5632; trans64(wo, wot, 2048, 2048, t & 31, t >> 5, tl);
  } else {
    // fused (cos,sin) float2 table: fcs[t*64+i] = (fc, fs) -- halves RoPE epilogue loads
    int base = (gid - 6656) * 2048 + threadIdx.x * 8;
#pragma unroll
    for (int j = 0; j < 8; j++) {
      int idx = base + j;
      fcs[idx] = make_float2(fc[idx], fs[idx]);
    }
  }
}

// ---------------- GEMM: C = A[M][K] x BT[N][K], 128x128 tile, BK=64, 4 waves ----------------
// MODE 0: C f32 [4096][2048] (O projection). grid (16,32).
// MODE 3: fused QKV. grid (24,32): bx<16 -> Q: rms+rope*(log2e/sqrt(D)) -> bf16 Cout;
//         bx 16..19 -> K: rms+rope -> Kout; bx 20..23 -> V: bf16^T -> Vout (b,kvh,d,t).
// XCD rectangle remap (r13): each XCD owns a 12x8 (MODE3) / 8x8 (MODE0) tile rectangle.
template <int MODE>
__global__ __launch_bounds__(256) void k_gemm(
    const u16* __restrict__ A, const u16* __restrict__ BT0, const u16* __restrict__ BT1,
    void* __restrict__ Cout, u16* __restrict__ Kout, u16* __restrict__ Vout, int K,
    const float* __restrict__ nwq, const float* __restrict__ nwk,
    const float2* __restrict__ fcs) {
  constexpr int NX = (MODE == 0) ? 16 : 24;
  constexpr int RBX = (MODE == 0) ? 8 : 12;   // rectangle width (bxt per XCD)
  __shared__ char lds[32768];
  char* As = lds; char* Bs = lds + 16384;
  int tid = threadIdx.x, w = tid >> 6, l = tid & 63, lg = l >> 4, ll = l & 15;
  // XCD rectangle remap (bijective): xcd = lid&7; 2 col-groups x 4 row-groups
  int lid = blockIdx.y * NX + blockIdx.x;
  int xcd = lid & 7, r = lid >> 3;            // r in 0..NWG/8-1
  int colg = xcd & 1, rowg = xcd >> 1;
  int bxt = colg * RBX + r % RBX;
  int bm0 = (rowg * 8 + r / RBX) * 128;
  bool qpath = (MODE == 0) || (bxt < 16);
  const u16* BT = qpath ? BT0 : BT1;
  int bn0 = qpath ? bxt * 128 : (bxt - 16) * 128;
  int wr = w >> 1, wc = w & 1;
  f32x4 acc[4][4] = {};
  for (int k0 = 0; k0 < K; k0 += 64) {
#pragma unroll
    for (int i = 0; i < 4; i++) {
      int base = i * 256 + (w << 6);       // wave-uniform chunk base
      int p = base + l;                    // this lane's 16B chunk
      int rr = p >> 3, kc = (p & 7) ^ (rr & 7);  // pre-swizzled global source
      gll16(A + (size_t)(bm0 + rr) * K + k0 + kc * 8, As + base * 16);
      gll16(BT + (size_t)(bn0 + rr) * K + k0 + kc * 8, Bs + base * 16);
    }
    asm volatile("s_waitcnt vmcnt(0)" ::: "memory");
    __syncthreads();
#pragma unroll
    for (int ks = 0; ks < 2; ks++) {
      bf16x8 af[4], bfr[4];
#pragma unroll
      for (int m = 0; m < 4; m++) {
        int row = 64 * wr + 16 * m + ll;
        af[m] = *(const bf16x8*)(As + row * 128 + (((lg + 4 * ks) ^ (row & 7)) << 4));
      }
#pragma unroll
      for (int n = 0; n < 4; n++) {
        int row = 64 * wc + 16 * n + ll;
        bfr[n] = *(const bf16x8*)(Bs + row * 128 + (((lg + 4 * ks) ^ (row & 7)) << 4));
      }
#pragma unroll
      for (int m = 0; m < 4; m++)
#pragma unroll
        for (int n = 0; n < 4; n++)
          acc[m][n] = __builtin_amdgcn_mfma_f32_16x16x32_bf16(af[m], bfr[n], acc[m][n], 0, 0, 0);
    }
    __syncthreads();
  }

  if (MODE == 0) {
    float* C = (float*)Cout;
#pragma unroll
    for (int m = 0; m < 4; m++)
#pragma unroll
      for (int n = 0; n < 4; n++) {
        int row = bm0 + 64 * wr + 16 * m + 4 * lg;
        int col = bn0 + 64 * wc + 16 * n + ll;
        float* cp = C + (size_t)row * 2048 + col;
#pragma unroll
        for (int r2 = 0; r2 < 4; r2++) cp[(size_t)r2 * 2048] = acc[m][n][r2];
      }
    return;
  }

  if (qpath || bn0 < 512) {
    // --- fused RMSNorm + RoPE + bf16 store (Q or K heads); all-lane straight-line
    // epilogue (r9-proven; half-lane predicated version regressed 24us -- r10 lesson) ---
    const float* nw = qpath ? nwq : nwk;
    u16* O = qpath ? (u16*)Cout : Kout;
    int ostride = qpath ? 2048 : 512;
    // Q: log2e/sqrt(128) (exp2-domain attention); K: 1
    float outscale = qpath ? 0.12751744843f : 1.0f;
    float* ssum = (float*)lds;  // [wr][64 rows][wc]
    float ps[4][4];
#pragma unroll
    for (int m = 0; m < 4; m++)
#pragma unroll
      for (int r2 = 0; r2 < 4; r2++) {
        float p = 0.f;
#pragma unroll
        for (int n = 0; n < 4; n++) p += acc[m][n][r2] * acc[m][n][r2];
#pragma unroll
        for (int msk = 1; msk < 16; msk <<= 1) p += __shfl_xor(p, msk);
        ps[m][r2] = p;
      }
    if (ll == 0) {
#pragma unroll
      for (int m = 0; m < 4; m++)
#pragma unroll
        for (int r2 = 0; r2 < 4; r2++)
          ssum[wr * 128 + (16 * m + 4 * lg + r2) * 2 + wc] = ps[m][r2];
    }
    __syncthreads();
    float rs[4][4];
#pragma unroll
    for (int m = 0; m < 4; m++)
#pragma unroll
      for (int r2 = 0; r2 < 4; r2++) {
        int rowl = 16 * m + 4 * lg + r2;
        float tot = ssum[wr * 128 + rowl * 2] + ssum[wr * 128 + rowl * 2 + 1];
        rs[m][r2] = rsqrtf(tot * (1.0f / 128.0f) + 1e-5f) * outscale;
      }
#pragma unroll
    for (int m = 0; m < 4; m++)
#pragma unroll
      for (int n = 0; n < 4; n++) {
        int d = 64 * wc + 16 * n + ll;     // dim within head (0..127)
        float wgt = nw[d];
        int i = d >> 1;
#pragma unroll
        for (int r2 = 0; r2 < 4; r2++) {
          int row = bm0 + 64 * wr + 16 * m + 4 * lg + r2;
          int t = row & 2047;
          float y = acc[m][n][r2] * rs[m][r2] * wgt;
          float p = __shfl_xor(y, 1);
          float2 cs = fcs[t * 64 + i];     // fused (cos,sin): one 8B load
          float o = (ll & 1) ? (p * cs.y + y * cs.x) : (y * cs.x - p * cs.y);
          O[(size_t)row * ostride + bn0 + d] = f2bf(o);
        }
      }
  } else {
    // --- V: bf16 + transpose to (b,kvh,d,t) via swizzled LDS ---
    int b = bm0 >> 11, t0g = bm0 & 2047;
    int kvh = (bn0 - 512) >> 7;
    int bk = b * 4 + kvh;
#pragma unroll
    for (int m = 0; m < 4; m++)
#pragma unroll
      for (int n = 0; n < 4; n++) {
        int d = 64 * wc + 16 * n + ll;
        int tloc = 64 * wr + 16 * m + 4 * lg;
        u32 w0 = pk2(acc[m][n][0], acc[m][n][1]);
        u32 w1 = pk2(acc[m][n][2], acc[m][n][3]);
        int byte = (d * 256 + tloc * 2) ^ ((d & 7) << 4);
        *(uint2*)(lds + byte) = make_uint2(w0, w1);
      }
    __syncthreads();
    int tc = tid & 15, dbase = tid >> 4;
#pragma unroll
    for (int pass = 0; pass < 8; pass++) {
      int d = dbase + pass * 16;
      int byte = (d * 256 + tc * 16) ^ ((d & 7) << 4);
      uint4 v = *(const uint4*)(lds + byte);
      *(uint4*)(Vout + ((size_t)(bk * 128 + d)) * 2048 + t0g + tc * 8) = v;
    }
  }
}

// ---------------- causal GQA flash attention (r11 structure + STATIC-normalizer softmax) ----------------
// 512 blocks: fid&7 -> (b,kvh) XCD grouping; block handles q-tiles {pairId, 31-pairId}.
// K/V double-buffered via global_load_lds w/ pre-swizzled source. STATIC softmax (r15):
// Q,K are RMS-normalized so |s| <= sqrt(128)*log2e*|wq||wk| ~ 16 (log2 units); f32 exp2
// headroom ~2^127 and fp relative precision is scale-invariant, so P = exp2(s) DIRECTLY
// and the normalizer cancels in O = (P V)/(P 1). Kills max-reduce (16 shfl + serial
// chain), defer branch, and all rescales. ones-MFMA row-sum, setprio.
// __launch_bounds__(256,4) caps VGPR 128 (r6/r8 lesson).
// NOTE r12/r13 lessons: KVBLK=32 doubles per-iter overhead + V-row bank conflicts;
// V-from-L2 serializes against the in-order vmcnt prefetch queue. Do not repeat.
__global__ __launch_bounds__(256, 4) void k_attn(
    const u16* __restrict__ Q, const u16* __restrict__ Kb,
    const u16* __restrict__ Vt, u16* __restrict__ Y) {
  __shared__ char lds[73728];  // K0 16K | V0 16K | K1 16K | V1 16K | P 8K
  char* Ps = lds + 65536;
  int tid = threadIdx.x, w = tid >> 6, l = tid & 63, lg = l >> 4, ll = l & 15;
  int fid = blockIdx.x;
  int g = fid & 7, rank = fid >> 3;
  int b = g >> 2, kvh = g & 3;
  int h = kvh * 4 + (rank & 3);
  int pairId = rank >> 2;  // 0..15
  const u16* Kbase = Kb + ((size_t)b * 2048) * 512 + kvh * 128;
  const u16* Vbase = Vt + ((size_t)(b * 4 + kvh) * 128) * 2048;

  const bf16x8 vones = {(short)0x3F80, (short)0x3F80, (short)0x3F80, (short)0x3F80,
                        (short)0x3F80, (short)0x3F80, (short)0x3F80, (short)0x3F80};

#pragma unroll 1
  for (int qi = 0; qi < 2; qi++) {
    int qb = qi ? (31 - pairId) : pairId;
    int q0 = qb * 64;
    bf16x8 qf[4];
    {
      int qrow = b * 2048 + q0 + 16 * w + ll;
      const u16* qp = Q + (size_t)qrow * 2048 + h * 128;
#pragma unroll
      for (int ks = 0; ks < 4; ks++) qf[ks] = *(const bf16x8*)(qp + ks * 32 + lg * 8);
    }
    f32x4 o[8] = {};
    f32x4 lacc = {};

    auto stage = [&](int bi, int k0) {
      char* Kd = lds + (bi ? 32768 : 0);
      char* Vd = lds + (bi ? 49152 : 16384);
#pragma unroll
      for (int i = 0; i < 4; i++) {
        int c = i * 256 + tid;
        int dst = (i * 256 + (w << 6)) * 16;  // wave-uniform chunk base * 16B
        int krow = c >> 4, ksrc = (c & 15) ^ (krow & 7);
        gll16(Kbase + (size_t)(k0 + krow) * 512 + ksrc * 8, Kd + dst);
        int vd = c >> 3, vsrc = (c & 7) ^ (vd & 7);
        gll16(Vbase + (size_t)vd * 2048 + k0 + vsrc * 8, Vd + dst);
      }
    };

    stage(0, 0);
    asm volatile("s_waitcnt vmcnt(0)" ::: "memory");
    __syncthreads();

    int cur = 0;
    for (int it = 0; it <= qb; ++it) {
      if (it < qb) stage(cur ^ 1, (it + 1) * 64);  // async prefetch next tile
      char* Ks = lds + (cur ? 32768 : 0);
      char* Vs = lds + (cur ? 49152 : 16384);
      // S = Q K^T (per wave: 16 q-rows x 64 kv); log2e/sqrt(D) pre-folded into Q
      f32x4 s[4] = {};
      __builtin_amdgcn_s_setprio(1);
#pragma unroll
      for (int ks = 0; ks < 4; ks++) {
#pragma unroll
        for (int n = 0; n < 4; n++) {
          int row = 16 * n + ll;
          bf16x8 kf = *(const bf16x8*)(Ks + ((row * 256 + (lg + 4 * ks) * 16) ^ ((row & 7) << 4)));
          s[n] = __builtin_amdgcn_mfma_f32_16x16x32_bf16(qf[ks], kf, s[n], 0, 0, 0);
        }
      }
      __builtin_amdgcn_s_setprio(0);
      if (it == qb) {  // diagonal tile: causal mask
        int k0 = it * 64;
#pragma unroll
        for (int n = 0; n < 4; n++) {
          int kk = k0 + 16 * n + ll;
#pragma unroll
          for (int r = 0; r < 4; r++) {
            int qq = q0 + 16 * w + 4 * lg + r;
            if (kk > qq) s[n][r] = -1e30f;
          }
        }
      }
      // STATIC-normalizer softmax: P = exp2(s) directly (no max, no rescale).
      // exp2f(-1e30) = 0 handles masked lanes.
#pragma unroll
      for (int r = 0; r < 4; r++) {
        int prow = 4 * lg + r;
#pragma unroll
        for (int n = 0; n < 4; n++) {
          float e = exp2f(s[n][r]);
          int byte = (w << 11) + ((prow * 128 + (16 * n + ll) * 2) ^ ((prow & 7) << 4));
          *(u16*)(Ps + byte) = f2bf_fast(e);
        }
      }
      // O += P V ; l += P 1 (row-sum on the MFMA pipe)
      __builtin_amdgcn_s_setprio(1);
#pragma unroll
      for (int ks = 0; ks < 2; ks++) {
        bf16x8 pf = *(const bf16x8*)(Ps + (w << 11) + ((ll * 128 + (lg + 4 * ks) * 16) ^ ((ll & 7) << 4)));
        lacc = __builtin_amdgcn_mfma_f32_16x16x32_bf16(pf, vones, lacc, 0, 0, 0);
#pragma unroll
        for (int n = 0; n < 8; n++) {
          int row = 16 * n + ll;
          bf16x8 vf = *(const bf16x8*)(Vs + ((row * 128 + (lg + 4 * ks) * 16) ^ ((row & 7) << 4)));
          o[n] = __builtin_amdgcn_mfma_f32_16x16x32_bf16(pf, vf, o[n], 0, 0, 0);
        }
      }
      __builtin_amdgcn_s_setprio(0);
      // drain this iteration's prefetch, publish to all waves
      asm volatile("s_waitcnt vmcnt(0)" ::: "memory");
      __syncthreads();
      cur ^= 1;
    }
    // output
    float rl[4];
#pragma unroll
    for (int r = 0; r < 4; r++) rl[r] = 1.0f / lacc[r];
#pragma unroll
    for (int n = 0; n < 8; n++) {
      int col = h * 128 + 16 * n + ll;
#pragma unroll
      for (int r = 0; r < 4; r++) {
        int trow = b * 2048 + q0 + 16 * w + 4 * lg + r;
        Y[(size_t)trow * 2048 + col] = f2bf_fast(o[n][r] * rl[r]);
      }
    }
  }
  (void)Vbase;
}

extern "C" void kernel_launch(void* const* d_in, const int* in_sizes, int n_in,
                              void* d_out, int out_size, void* d_ws, size_t ws_size,
                              hipStream_t stream) {
  const float* x   = (const float*)d_in[0];
  const float* fc  = (const float*)d_in[1];
  const float* fs  = (const float*)d_in[2];
  const float* wq  = (const float*)d_in[3];
  const float* wk  = (const float*)d_in[4];
  const float* wv  = (const float*)d_in[5];
  const float* wo  = (const float*)d_in[6];
  const float* qnw = (const float*)d_in[7];
  const float* knw = (const float*)d_in[8];
  float* out = (float*)d_out;

  const size_t MB = 1ull << 20;
  char* ws = (char*)d_ws;
  u16*    xb   = (u16*)(ws);             // 16 MB  x bf16
  u16*    wqt  = (u16*)(ws + 16 * MB);   //  8 MB  wq^T bf16 [2048][2048]
  u16*    wkvt = (u16*)(ws + 24 * MB);   //  4 MB  [wk^T;wv^T] bf16 [1024][2048]
  u16*    wot  = (u16*)(ws + 28 * MB);   //  8 MB  wo^T bf16
  u16*    Qb   = (u16*)(ws + 36 * MB);   // 16 MB  Q' bf16 (rms+rope, x log2e/sqrt(D))
  u16*    Kbq  = (u16*)(ws + 52 * MB);   //  4 MB  K' bf16 (rms+rope)
  u16*    Vtg  = (u16*)(ws + 56 * MB);   //  4 MB  V^T bf16 (b,kvh,d,t)
  u16*    Yb   = (u16*)(ws + 60 * MB);   // 16 MB  attn out bf16
  float2* fcs  = (float2*)(ws + 76 * MB);//  1 MB  fused (cos,sin) table

  hipLaunchKernelGGL(k_prep, dim3(6720), dim3(256), 0, stream,
                     x, xb, wq, wqt, wk, wv, wkvt, wo, wot, fc, fs, fcs);
  // fused QKV projection: Q (rms+rope+log2e-scale), K (rms+rope), V (transpose)
  hipLaunchKernelGGL((k_gemm<3>), dim3(24, 32), dim3(256), 0, stream,
                     xb, wqt, wkvt, (void*)Qb, Kbq, Vtg, 2048,
                     qnw, knw, fcs);
  hipLaunchKernelGGL(k_attn, dim3(512), dim3(256), 0, stream, Qb, Kbq, Vtg, Yb);
  hipLaunchKernelGGL((k_gemm<0>), dim3(16, 32), dim3(256), 0, stream,
                     Yb, wot, (const u16*)nullptr, (void*)out, (u16*)nullptr, (u16*)nullptr, 2048,
                     nullptr, nullptr, nullptr);
}

// Round 16
// 207.455 us; speedup vs baseline: 1.8759x; 1.0413x over previous
//
#include <hip/hip_runtime.h>
#include <hip/hip_bf16.h>

using u16 = unsigned short;
using u32 = unsigned int;

typedef short bf16x8 __attribute__((ext_vector_type(8)));
typedef float f32x4 __attribute__((ext_vector_type(4)));

#define AS1 __attribute__((address_space(1)))
#define AS3 __attribute__((address_space(3)))

__device__ __forceinline__ void gll16(const void* g, void* l) {
  __builtin_amdgcn_global_load_lds((const AS1 u32*)g, (AS3 u32*)l, 16, 0, 0);
}

__device__ __forceinline__ u16 f2bf(float x) {  // round-to-nearest-even bf16
  u32 u = __builtin_bit_cast(u32, x);
  u32 r = (u + 0x7fffu + ((u >> 16) & 1u)) >> 16;
  return (u16)r;
}
__device__ __forceinline__ u32 pk2(float lo, float hi) {
  return (u32)f2bf(lo) | ((u32)f2bf(hi) << 16);
}
__device__ __forceinline__ u16 f2bf_fast(float x) {  // hw cvt (validated r5/r6)
  __hip_bfloat16 h = __float2bfloat16(x);
  return __builtin_bit_cast(u16, h);
}

// ---------------- merged prep: x cast + 4 weight transposes + fused cos/sin table ----------------
__device__ __forceinline__ void trans64(const float* __restrict__ in, u16* __restrict__ out,
                                        int R, int Cc, int bx, int by, float (*tl)[65]) {
  int c0 = bx * 64, r0 = by * 64, tid = threadIdx.x;
#pragma unroll
  for (int i = 0; i < 16; i++) {
    int idx = i * 256 + tid; int tr = idx >> 6, tc = idx & 63;
    tl[tr][tc] = in[(size_t)(r0 + tr) * Cc + c0 + tc];
  }
  __syncthreads();
#pragma unroll
  for (int i = 0; i < 16; i++) {
    int idx = i * 256 + tid; int tr = idx >> 6, tc = idx & 63;
    out[(size_t)(c0 + tr) * R + r0 + tc] = f2bf(tl[tc][tr]);
  }
}

__global__ void k_prep(const float* __restrict__ x, u16* __restrict__ xb,
                       const float* __restrict__ wq, u16* __restrict__ wqt,
                       const float* __restrict__ wk, const float* __restrict__ wv,
                       u16* __restrict__ wkvt,
                       const float* __restrict__ wo, u16* __restrict__ wot,
                       const float* __restrict__ fc, const float* __restrict__ fs,
                       float2* __restrict__ fcs) {
  __shared__ float tl[64][65];
  int gid = blockIdx.x;
  if (gid < 4096) {
    int i = gid * 256 + threadIdx.x;
    const float4* p = (const float4*)(x + (size_t)i * 8);
    float4 a = p[0], b = p[1];
    uint4 o;
    o.x = pk2(a.x, a.y); o.y = pk2(a.z, a.w);
    o.z = pk2(b.x, b.y); o.w = pk2(b.z, b.w);
    *(uint4*)(xb + (size_t)i * 8) = o;
  } else if (gid < 5120) {
    int t = gid - 4096; trans64(wq, wqt, 2048, 2048, t & 31, t >> 5, tl);
  } else if (gid < 5376) {
    int t = gid - 5120; trans64(wk, wkvt, 2048, 512, t & 7, t >> 3, tl);
  } else if (gid < 5632) {
    int t = gid - 5376; trans64(wv, wkvt + 512 * 2048, 2048, 512, t & 7, t >> 3, tl);
  } else if (gid < 6656) {
    int t = gid - 5632; trans64(wo, wot, 2048, 2048, t & 31, t >> 5, tl);
  } else {
    // fused (cos,sin) float2 table
    int base = (gid - 6656) * 2048 + threadIdx.x * 8;
#pragma unroll
    for (int j = 0; j < 8; j++) {
      int idx = base + j;
      fcs[idx] = make_float2(fc[idx], fs[idx]);
    }
  }
}

// ---------------- O-projection GEMM (proven r15 path, MODE 0 only) ----------------
template <int MODE>
__global__ __launch_bounds__(256) void k_gemm(
    const u16* __restrict__ A, const u16* __restrict__ BT0, const u16* __restrict__ BT1,
    void* __restrict__ Cout, u16* __restrict__ Kout, u16* __restrict__ Vout, int K,
    const float* __restrict__ nwq, const float* __restrict__ nwk,
    const float2* __restrict__ fcs) {
  constexpr int NX = 16;
  constexpr int RBX = 8;
  __shared__ char lds[32768];
  char* As = lds; char* Bs = lds + 16384;
  int tid = threadIdx.x, w = tid >> 6, l = tid & 63, lg = l >> 4, ll = l & 15;
  int lid = blockIdx.y * NX + blockIdx.x;
  int xcd = lid & 7, r = lid >> 3;
  int colg = xcd & 1, rowg = xcd >> 1;
  int bxt = colg * RBX + r % RBX;
  int bm0 = (rowg * 8 + r / RBX) * 128;
  const u16* BT = BT0;
  int bn0 = bxt * 128;
  int wr = w >> 1, wc = w & 1;
  f32x4 acc[4][4] = {};
  for (int k0 = 0; k0 < K; k0 += 64) {
#pragma unroll
    for (int i = 0; i < 4; i++) {
      int base = i * 256 + (w << 6);
      int p = base + l;
      int rr = p >> 3, kc = (p & 7) ^ (rr & 7);
      gll16(A + (size_t)(bm0 + rr) * K + k0 + kc * 8, As + base * 16);
      gll16(BT + (size_t)(bn0 + rr) * K + k0 + kc * 8, Bs + base * 16);
    }
    asm volatile("s_waitcnt vmcnt(0)" ::: "memory");
    __syncthreads();
#pragma unroll
    for (int ks = 0; ks < 2; ks++) {
      bf16x8 af[4], bfr[4];
#pragma unroll
      for (int m = 0; m < 4; m++) {
        int row = 64 * wr + 16 * m + ll;
        af[m] = *(const bf16x8*)(As + row * 128 + (((lg + 4 * ks) ^ (row & 7)) << 4));
      }
#pragma unroll
      for (int n = 0; n < 4; n++) {
        int row = 64 * wc + 16 * n + ll;
        bfr[n] = *(const bf16x8*)(Bs + row * 128 + (((lg + 4 * ks) ^ (row & 7)) << 4));
      }
#pragma unroll
      for (int m = 0; m < 4; m++)
#pragma unroll
        for (int n = 0; n < 4; n++)
          acc[m][n] = __builtin_amdgcn_mfma_f32_16x16x32_bf16(af[m], bfr[n], acc[m][n], 0, 0, 0);
    }
    __syncthreads();
  }
  float* C = (float*)Cout;
#pragma unroll
  for (int m = 0; m < 4; m++)
#pragma unroll
    for (int n = 0; n < 4; n++) {
      int row = bm0 + 64 * wr + 16 * m + 4 * lg;
      int col = bn0 + 64 * wc + 16 * n + ll;
      float* cp = C + (size_t)row * 2048 + col;
#pragma unroll
      for (int r2 = 0; r2 < 4; r2++) cp[(size_t)r2 * 2048] = acc[m][n][r2];
    }
  (void)nwq; (void)nwk; (void)fcs; (void)Kout; (void)Vout;
}

// ---------------- QKV GEMM: 3-stage counted-vmcnt pipeline (r16) ----------------
// 512 threads (8 waves = 2/SIMD), 128x128 tile, BK=64, 3x32KB stage buffers (96KB,
// 1 block/CU). Lookahead-2 prefetch: iter kt issues tile kt+2 (4 vmem/wave); end-of-iter
// waits vmcnt(4) (just-issued 4 stay in flight; waits only for tile kt+1 issued a full
// iter earlier) + raw s_barrier + sched_barrier(0). WAR safe: stage at kt writes
// buf[(kt-1)%3], whose readers passed the iter-(kt-1) barrier. Tail iters drain vmcnt(0).
// Wave grid 2(wr)x4(wc): per-wave 64 rows x 32 cols, acc[4][2].
// Epilogues: Q/K rmsnorm (4-way cross-wave ssum) + rope; V bf16^T via swizzled LDS.
__global__ __launch_bounds__(512, 2) void k_gemm_qkv(
    const u16* __restrict__ A, const u16* __restrict__ BT0, const u16* __restrict__ BT1,
    u16* __restrict__ Qout, u16* __restrict__ Kout, u16* __restrict__ Vout,
    const float* __restrict__ nwq, const float* __restrict__ nwk,
    const float2* __restrict__ fcs) {
  __shared__ char lds[98304];  // 3 stages x (A 16K | B 16K)
  const int K = 2048;
  int tid = threadIdx.x, w = tid >> 6, l = tid & 63, lg = l >> 4, ll = l & 15;
  int wr = w >> 2, wc = w & 3;
  // XCD rectangle remap (12 bxt x 8 bm per XCD), bijective over 768 blocks
  int lid = blockIdx.y * 24 + blockIdx.x;
  int xcd = lid & 7, r = lid >> 3;
  int colg = xcd & 1, rowg = xcd >> 1;
  int bxt = colg * 12 + r % 12;
  int bm0 = (rowg * 8 + r / 12) * 128;
  bool qpath = (bxt < 16);
  const u16* BT = qpath ? BT0 : BT1;
  int bn0 = qpath ? bxt * 128 : (bxt - 16) * 128;

  auto stage = [&](int si, int kt) {
    char* Sb = lds + si * 32768;
    int k0 = kt * 64;
#pragma unroll
    for (int i = 0; i < 2; i++) {
      int base = i * 512 + (w << 6) + ((tid >> 8) << 8);  // careful: 512 thr
      // NOTE: with 512 threads, chunk id c = i*512 + tid; wave-uniform base must be
      // (i*512 + w*64). tid = w*64 + l, w in 0..7 -> base = i*512 + w*64 works directly.
      base = i * 512 + (w << 6);
      int c = base + l;
      int row = c >> 3, kc = (c & 7) ^ (row & 7);
      gll16(A + (size_t)(bm0 + row) * K + k0 + kc * 8, Sb + base * 16);
      gll16(BT + (size_t)(bn0 + row) * K + k0 + kc * 8, Sb + 16384 + base * 16);
    }
  };

  f32x4 acc[4][2] = {};
  stage(0, 0); stage(1, 1);
  asm volatile("s_waitcnt vmcnt(4)" ::: "memory");  // tile0 landed (tile1's 4 may fly)
  __builtin_amdgcn_s_barrier();
  __builtin_amdgcn_sched_barrier(0);

  for (int kt = 0; kt < 32; ++kt) {
    int cs = kt % 3;
    if (kt + 2 < 32) stage((kt + 2) % 3, kt + 2);  // async prefetch 2 ahead
    char* As = lds + cs * 32768;
    char* Bs = As + 16384;
    __builtin_amdgcn_s_setprio(1);
#pragma unroll
    for (int ks = 0; ks < 2; ks++) {
      bf16x8 af[4], bf[2];
#pragma unroll
      for (int m = 0; m < 4; m++) {
        int row = 64 * wr + 16 * m + ll;
        af[m] = *(const bf16x8*)(As + row * 128 + (((lg + 4 * ks) ^ (row & 7)) << 4));
      }
#pragma unroll
      for (int n = 0; n < 2; n++) {
        int row = 32 * wc + 16 * n + ll;
        bf[n] = *(const bf16x8*)(Bs + row * 128 + (((lg + 4 * ks) ^ (row & 7)) << 4));
      }
#pragma unroll
      for (int m = 0; m < 4; m++)
#pragma unroll
        for (int n = 0; n < 2; n++)
          acc[m][n] = __builtin_amdgcn_mfma_f32_16x16x32_bf16(af[m], bf[n], acc[m][n], 0, 0, 0);
    }
    __builtin_amdgcn_s_setprio(0);
    if (kt + 2 < 32) {
      asm volatile("s_waitcnt vmcnt(4)" ::: "memory");  // tile kt+1 landed; kt+2 in flight
    } else {
      asm volatile("s_waitcnt vmcnt(0)" ::: "memory");  // tail: drain
    }
    __builtin_amdgcn_s_barrier();
    __builtin_amdgcn_sched_barrier(0);
  }

  if (qpath || bn0 < 512) {
    // --- fused RMSNorm + RoPE + bf16 store (Q or K heads) ---
    const float* nw = qpath ? nwq : nwk;
    u16* O = qpath ? Qout : Kout;
    int ostride = qpath ? 2048 : 512;
    float outscale = qpath ? 0.12751744843f : 1.0f;  // log2e/sqrt(128) for Q
    float* ssum = (float*)lds;  // [wr 2][row 64][wc 4] f32 = 2KB (stage bufs dead)
    float ps[4][4];
#pragma unroll
    for (int m = 0; m < 4; m++)
#pragma unroll
      for (int r2 = 0; r2 < 4; r2++) {
        float p = 0.f;
#pragma unroll
        for (int n = 0; n < 2; n++) p += acc[m][n][r2] * acc[m][n][r2];
#pragma unroll
        for (int msk = 1; msk < 16; msk <<= 1) p += __shfl_xor(p, msk);
        ps[m][r2] = p;
      }
    if (ll == 0) {
#pragma unroll
      for (int m = 0; m < 4; m++)
#pragma unroll
        for (int r2 = 0; r2 < 4; r2++)
          ssum[wr * 256 + (16 * m + 4 * lg + r2) * 4 + wc] = ps[m][r2];
    }
    __syncthreads();
    float rs[4][4];
#pragma unroll
    for (int m = 0; m < 4; m++)
#pragma unroll
      for (int r2 = 0; r2 < 4; r2++) {
        int rowl = 16 * m + 4 * lg + r2;
        const float* sp = ssum + wr * 256 + rowl * 4;
        float tot = sp[0] + sp[1] + sp[2] + sp[3];
        rs[m][r2] = rsqrtf(tot * (1.0f / 128.0f) + 1e-5f) * outscale;
      }
#pragma unroll
    for (int m = 0; m < 4; m++)
#pragma unroll
      for (int n = 0; n < 2; n++) {
        int col = bn0 + 32 * wc + 16 * n + ll;
        int d = col & 127;                 // dim within head
        float wgt = nw[d];
        int i = d >> 1;
#pragma unroll
        for (int r2 = 0; r2 < 4; r2++) {
          int row = bm0 + 64 * wr + 16 * m + 4 * lg + r2;
          int t = row & 2047;
          float y = acc[m][n][r2] * rs[m][r2] * wgt;
          float p = __shfl_xor(y, 1);
          float2 cs = fcs[t * 64 + i];
          float o = (ll & 1) ? (p * cs.y + y * cs.x) : (y * cs.x - p * cs.y);
          O[(size_t)row * ostride + col] = f2bf(o);
        }
      }
  } else {
    // --- V: bf16 + transpose to (b,kvh,d,t) via swizzled LDS ---
    int b = bm0 >> 11, t0g = bm0 & 2047;
    int kvh = (bn0 - 512) >> 7;
    int bk = b * 4 + kvh;
#pragma unroll
    for (int m = 0; m < 4; m++)
#pragma unroll
      for (int n = 0; n < 2; n++) {
        int d = 32 * wc + 16 * n + ll;
        int tloc = 64 * wr + 16 * m + 4 * lg;
        u32 w0 = pk2(acc[m][n][0], acc[m][n][1]);
        u32 w1 = pk2(acc[m][n][2], acc[m][n][3]);
        int byte = (d * 256 + tloc * 2) ^ ((d & 7) << 4);
        *(uint2*)(lds + byte) = make_uint2(w0, w1);
      }
    __syncthreads();
    int tc = tid & 15, dbase = tid >> 4;  // dbase 0..31 (512 thr)
#pragma unroll
    for (int pass = 0; pass < 4; pass++) {
      int d = dbase + pass * 32;
      int byte = (d * 256 + tc * 16) ^ ((d & 7) << 4);
      uint4 v = *(const uint4*)(lds + byte);
      *(uint4*)(Vout + ((size_t)(bk * 128 + d)) * 2048 + t0g + tc * 8) = v;
    }
  }
}

// ---------------- causal GQA flash attention (r15-proven: static softmax) ----------------
__global__ __launch_bounds__(256, 4) void k_attn(
    const u16* __restrict__ Q, const u16* __restrict__ Kb,
    const u16* __restrict__ Vt, u16* __restrict__ Y) {
  __shared__ char lds[73728];  // K0 16K | V0 16K | K1 16K | V1 16K | P 8K
  char* Ps = lds + 65536;
  int tid = threadIdx.x, w = tid >> 6, l = tid & 63, lg = l >> 4, ll = l & 15;
  int fid = blockIdx.x;
  int g = fid & 7, rank = fid >> 3;
  int b = g >> 2, kvh = g & 3;
  int h = kvh * 4 + (rank & 3);
  int pairId = rank >> 2;  // 0..15
  const u16* Kbase = Kb + ((size_t)b * 2048) * 512 + kvh * 128;
  const u16* Vbase = Vt + ((size_t)(b * 4 + kvh) * 128) * 2048;

  const bf16x8 vones = {(short)0x3F80, (short)0x3F80, (short)0x3F80, (short)0x3F80,
                        (short)0x3F80, (short)0x3F80, (short)0x3F80, (short)0x3F80};

#pragma unroll 1
  for (int qi = 0; qi < 2; qi++) {
    int qb = qi ? (31 - pairId) : pairId;
    int q0 = qb * 64;
    bf16x8 qf[4];
    {
      int qrow = b * 2048 + q0 + 16 * w + ll;
      const u16* qp = Q + (size_t)qrow * 2048 + h * 128;
#pragma unroll
      for (int ks = 0; ks < 4; ks++) qf[ks] = *(const bf16x8*)(qp + ks * 32 + lg * 8);
    }
    f32x4 o[8] = {};
    f32x4 lacc = {};

    auto stage = [&](int bi, int k0) {
      char* Kd = lds + (bi ? 32768 : 0);
      char* Vd = lds + (bi ? 49152 : 16384);
#pragma unroll
      for (int i = 0; i < 4; i++) {
        int c = i * 256 + tid;
        int dst = (i * 256 + (w << 6)) * 16;
        int krow = c >> 4, ksrc = (c & 15) ^ (krow & 7);
        gll16(Kbase + (size_t)(k0 + krow) * 512 + ksrc * 8, Kd + dst);
        int vd = c >> 3, vsrc = (c & 7) ^ (vd & 7);
        gll16(Vbase + (size_t)vd * 2048 + k0 + vsrc * 8, Vd + dst);
      }
    };

    stage(0, 0);
    asm volatile("s_waitcnt vmcnt(0)" ::: "memory");
    __syncthreads();

    int cur = 0;
    for (int it = 0; it <= qb; ++it) {
      if (it < qb) stage(cur ^ 1, (it + 1) * 64);
      char* Ks = lds + (cur ? 32768 : 0);
      char* Vs = lds + (cur ? 49152 : 16384);
      f32x4 s[4] = {};
      __builtin_amdgcn_s_setprio(1);
#pragma unroll
      for (int ks = 0; ks < 4; ks++) {
#pragma unroll
        for (int n = 0; n < 4; n++) {
          int row = 16 * n + ll;
          bf16x8 kf = *(const bf16x8*)(Ks + ((row * 256 + (lg + 4 * ks) * 16) ^ ((row & 7) << 4)));
          s[n] = __builtin_amdgcn_mfma_f32_16x16x32_bf16(qf[ks], kf, s[n], 0, 0, 0);
        }
      }
      __builtin_amdgcn_s_setprio(0);
      if (it == qb) {  // diagonal tile: causal mask
        int k0 = it * 64;
#pragma unroll
        for (int n = 0; n < 4; n++) {
          int kk = k0 + 16 * n + ll;
#pragma unroll
          for (int r = 0; r < 4; r++) {
            int qq = q0 + 16 * w + 4 * lg + r;
            if (kk > qq) s[n][r] = -1e30f;
          }
        }
      }
      // STATIC-normalizer softmax: P = exp2(s) directly
#pragma unroll
      for (int r = 0; r < 4; r++) {
        int prow = 4 * lg + r;
#pragma unroll
        for (int n = 0; n < 4; n++) {
          float e = exp2f(s[n][r]);
          int byte = (w << 11) + ((prow * 128 + (16 * n + ll) * 2) ^ ((prow & 7) << 4));
          *(u16*)(Ps + byte) = f2bf_fast(e);
        }
      }
      __builtin_amdgcn_s_setprio(1);
#pragma unroll
      for (int ks = 0; ks < 2; ks++) {
        bf16x8 pf = *(const bf16x8*)(Ps + (w << 11) + ((ll * 128 + (lg + 4 * ks) * 16) ^ ((ll & 7) << 4)));
        lacc = __builtin_amdgcn_mfma_f32_16x16x32_bf16(pf, vones, lacc, 0, 0, 0);
#pragma unroll
        for (int n = 0; n < 8; n++) {
          int row = 16 * n + ll;
          bf16x8 vf = *(const bf16x8*)(Vs + ((row * 128 + (lg + 4 * ks) * 16) ^ ((row & 7) << 4)));
          o[n] = __builtin_amdgcn_mfma_f32_16x16x32_bf16(pf, vf, o[n], 0, 0, 0);
        }
      }
      __builtin_amdgcn_s_setprio(0);
      asm volatile("s_waitcnt vmcnt(0)" ::: "memory");
      __syncthreads();
      cur ^= 1;
    }
    float rl[4];
#pragma unroll
    for (int r = 0; r < 4; r++) rl[r] = 1.0f / lacc[r];
#pragma unroll
    for (int n = 0; n < 8; n++) {
      int col = h * 128 + 16 * n + ll;
#pragma unroll
      for (int r = 0; r < 4; r++) {
        int trow = b * 2048 + q0 + 16 * w + 4 * lg + r;
        Y[(size_t)trow * 2048 + col] = f2bf_fast(o[n][r] * rl[r]);
      }
    }
  }
  (void)Vbase;
}

extern "C" void kernel_launch(void* const* d_in, const int* in_sizes, int n_in,
                              void* d_out, int out_size, void* d_ws, size_t ws_size,
                              hipStream_t stream) {
  const float* x   = (const float*)d_in[0];
  const float* fc  = (const float*)d_in[1];
  const float* fs  = (const float*)d_in[2];
  const float* wq  = (const float*)d_in[3];
  const float* wk  = (const float*)d_in[4];
  const float* wv  = (const float*)d_in[5];
  const float* wo  = (const float*)d_in[6];
  const float* qnw = (const float*)d_in[7];
  const float* knw = (const float*)d_in[8];
  float* out = (float*)d_out;

  const size_t MB = 1ull << 20;
  char* ws = (char*)d_ws;
  u16*    xb   = (u16*)(ws);             // 16 MB  x bf16
  u16*    wqt  = (u16*)(ws + 16 * MB);   //  8 MB  wq^T bf16 [2048][2048]
  u16*    wkvt = (u16*)(ws + 24 * MB);   //  4 MB  [wk^T;wv^T] bf16 [1024][2048]
  u16*    wot  = (u16*)(ws + 28 * MB);   //  8 MB  wo^T bf16
  u16*    Qb   = (u16*)(ws + 36 * MB);   // 16 MB  Q' bf16 (rms+rope, x log2e/sqrt(D))
  u16*    Kbq  = (u16*)(ws + 52 * MB);   //  4 MB  K' bf16 (rms+rope)
  u16*    Vtg  = (u16*)(ws + 56 * MB);   //  4 MB  V^T bf16 (b,kvh,d,t)
  u16*    Yb   = (u16*)(ws + 60 * MB);   // 16 MB  attn out bf16
  float2* fcs  = (float2*)(ws + 76 * MB);//  1 MB  fused (cos,sin) table

  hipLaunchKernelGGL(k_prep, dim3(6720), dim3(256), 0, stream,
                     x, xb, wq, wqt, wk, wv, wkvt, wo, wot, fc, fs, fcs);
  // fused QKV projection: 3-stage counted-vmcnt pipeline (512 thr)
  hipLaunchKernelGGL(k_gemm_qkv, dim3(24, 32), dim3(512), 0, stream,
                     xb, wqt, wkvt, Qb, Kbq, Vtg, qnw, knw, fcs);
  hipLaunchKernelGGL(k_attn, dim3(512), dim3(256), 0, stream, Qb, Kbq, Vtg, Yb);
  hipLaunchKernelGGL((k_gemm<0>), dim3(16, 32), dim3(256), 0, stream,
                     Yb, wot, (const u16*)nullptr, (void*)out, (u16*)nullptr, (u16*)nullptr, 2048,
                     nullptr, nullptr, nullptr);
}